// Round 19
// baseline (577.804 us; speedup 1.0000x reference)
//
#include <hip/hip_runtime.h>
#include <hip/hip_bf16.h>
#include <math.h>

#define SCALE_ 0.17677669529663687f
typedef float v2f __attribute__((ext_vector_type(2)));

// two independent IEEE FMAs per instr; op_sel broadcasts a.lo / a.hi to both
// halves. Per-element order and rounding identical to scalar => bit-exact.
__device__ __forceinline__ void pk_lo(v2f& acc, v2f a, v2f b) {
  asm("v_pk_fma_f32 %0, %1, %2, %0 op_sel:[0,0,0] op_sel_hi:[0,1,1]"
      : "+v"(acc) : "v"(a), "v"(b));
}
__device__ __forceinline__ void pk_hi(v2f& acc, v2f a, v2f b) {
  asm("v_pk_fma_f32 %0, %1, %2, %0 op_sel:[1,0,0] op_sel_hi:[1,1,1]"
      : "+v"(acc) : "v"(a), "v"(b));
}

// fused: rope table (blocks 0-31) + per-ball pos mean (blocks 32-47)
__global__ __launch_bounds__(256) void k_pre(const float* __restrict__ pos,
                                             float* __restrict__ rope,
                                             float* __restrict__ pm) {
  __shared__ float ps[1536];
  if (blockIdx.x < 32) {
    int i = blockIdx.x * 256 + threadIdx.x;  // 8192
    int t = i >> 4, j = i & 15;
    float inv = powf(10000.f, -(float)j / 16.f);
    float ang = (float)t * inv;
    rope[2 * i]     = cosf(ang);
    rope[2 * i + 1] = sinf(ang);
  } else {
    int ball = blockIdx.x - 32;
    for (int i = threadIdx.x; i < 1536; i += 256) ps[i] = pos[(size_t)ball * 1536 + i];
    __syncthreads();
    if (threadIdx.x < 3) {
      int c = threadIdx.x;
      float s = 0.f;
      for (int t = 0; t < 512; ++t) s += ps[t * 3 + c];  // EXACT t-ascending (sel-sensitive)
      pm[ball * 3 + c] = s * (1.f / 512.f);
    }
  }
}

// hn + fused gates. EXACT sequential ss sum per token (sel-sensitive).
__global__ __launch_bounds__(256) void k_hn(const float* __restrict__ x,
                                            const float* __restrict__ pos,
                                            const float* __restrict__ pm,
                                            const float* __restrict__ Wpe,
                                            const float* __restrict__ bpe,
                                            const float* __restrict__ rmsw,
                                            const float* __restrict__ Wg,
                                            float* __restrict__ hn,
                                            float* __restrict__ gates) {
  __shared__ float hx[32][257];
  __shared__ float rr[32][3];
  __shared__ float invs[32];
  int tb = blockIdx.x * 32;  // 256 blocks
  if (threadIdx.x < 96) {
    int tok = threadIdx.x / 3, c = threadIdx.x % 3;
    rr[tok][c] = pos[(size_t)(tb + tok) * 3 + c] - pm[((tb + tok) >> 9) * 3 + c];
  }
  __syncthreads();
  for (int i = threadIdx.x; i < 8192; i += 256) {
    int tok = i >> 8, d = i & 255;
    float h = x[(size_t)(tb + tok) * 256 + d] + rr[tok][0] * Wpe[d] + rr[tok][1] * Wpe[256 + d]
            + rr[tok][2] * Wpe[512 + d] + bpe[d];
    hx[tok][d] = h;
  }
  __syncthreads();
  if (threadIdx.x < 32) {
    int tok = threadIdx.x;
    float ss = 0.f;
    for (int d = 0; d < 256; ++d) { float h = hx[tok][d]; ss += h * h; }
    invs[tok] = 1.f / sqrtf(ss * (1.f / 256.f) + 1e-6f);
  }
  __syncthreads();
  for (int i = threadIdx.x; i < 8192; i += 256) {
    int tok = i >> 8, d = i & 255;
    float hv = hx[tok][d] * invs[tok] * rmsw[d];
    hn[(size_t)(tb + tok) * 256 + d] = hv;
    hx[tok][d] = hv;
  }
  __syncthreads();
  for (int g = threadIdx.x; g < 768; g += 256) {
    int tok = g / 24, j = g % 24;
    float s = 0.f;
    for (int d = 0; d < 256; ++d) s += hx[tok][d] * Wg[d * 24 + j];
    gates[(size_t)(tb + tok) * 24 + j] = 1.f / (1.f + expf(-s));
  }
}

// qkv = hn @ Wqkv, 64x64, untransposed A (broadcast reads), pk_fma, fused RoPE.
__global__ __launch_bounds__(256) void k_qkv(const float* __restrict__ A,
                                             const float* __restrict__ B,
                                             const float* __restrict__ rope,
                                             float* __restrict__ qo,
                                             float* __restrict__ ko,
                                             float* __restrict__ vo,
                                             float* __restrict__ rqo,
                                             float* __restrict__ rko) {
  __shared__ float As[64][33];
  __shared__ __align__(16) float Bs[32][68];
  const int bid = blockIdx.x;            // 1536 = 8 xcd * 16 m * 12 n
  const int xcd = bid & 7;
  const int idx = bid >> 3;
  const int m0 = (xcd * 16 + (idx & 15)) * 64;
  const int n0 = (idx >> 4) * 64;
  const int tid = threadIdx.x;
  const int tx = tid & 15, ty = tid >> 4;
  v2f acc2[4][2] = {};
  for (int k0 = 0; k0 < 256; k0 += 32) {
#pragma unroll
    for (int i = 0; i < 2; ++i) {
      int li = tid + i * 256;
      int mm = li >> 3, c4 = li & 7;
      float4 a4 = *reinterpret_cast<const float4*>(&A[(size_t)(m0 + mm) * 256 + k0 + c4 * 4]);
      As[mm][c4 * 4 + 0] = a4.x; As[mm][c4 * 4 + 1] = a4.y;
      As[mm][c4 * 4 + 2] = a4.z; As[mm][c4 * 4 + 3] = a4.w;
    }
#pragma unroll
    for (int i = 0; i < 2; ++i) {
      int li = tid + i * 256;
      int r = li >> 4, c4 = li & 15;
      float4 b4 = *reinterpret_cast<const float4*>(&B[(size_t)(k0 + r) * 768 + n0 + c4 * 4]);
      *reinterpret_cast<float4*>(&Bs[r][c4 * 4]) = b4;
    }
    __syncthreads();
#pragma unroll
    for (int kk = 0; kk < 32; ++kk) {
      float a0 = As[ty * 4 + 0][kk], a1 = As[ty * 4 + 1][kk];
      float a2 = As[ty * 4 + 2][kk], a3 = As[ty * 4 + 3][kk];
      float4 b4 = *reinterpret_cast<const float4*>(&Bs[kk][tx * 4]);
      v2f a01 = {a0, a1}, a23 = {a2, a3};
      v2f blo = {b4.x, b4.y}, bhi = {b4.z, b4.w};
      pk_lo(acc2[0][0], a01, blo); pk_lo(acc2[0][1], a01, bhi);
      pk_hi(acc2[1][0], a01, blo); pk_hi(acc2[1][1], a01, bhi);
      pk_lo(acc2[2][0], a23, blo); pk_lo(acc2[2][1], a23, bhi);
      pk_hi(acc2[3][0], a23, blo); pk_hi(acc2[3][1], a23, bhi);
    }
    __syncthreads();
  }
#pragma unroll
  for (int i = 0; i < 4; ++i) {
    int row = m0 + ty * 4 + i;
    int nb = row >> 9, t = row & 511;
#pragma unroll
    for (int j = 0; j < 4; j += 2) {
      int col = n0 + tx * 4 + j;
      int which = col >> 8, cj = col & 255;
      int h = cj >> 5, d = cj & 31;
      float v1 = (j == 0) ? acc2[i][0].x : acc2[i][1].x;
      float v2 = (j == 0) ? acc2[i][0].y : acc2[i][1].y;
      size_t base = ((size_t)(nb * 8 + h) * 512 + t) * 32 + d;
      if (which == 0) {
        qo[base] = v1; qo[base + 1] = v2;
        int p = d >> 1;
        float cc = rope[(t * 16 + p) * 2], ss = rope[(t * 16 + p) * 2 + 1];
        rqo[base] = v1 * cc - v2 * ss; rqo[base + 1] = v1 * ss + v2 * cc;
      } else if (which == 1) {
        ko[base] = v1; ko[base + 1] = v2;
        int p = d >> 1;
        float cc = rope[(t * 16 + p) * 2], ss = rope[(t * 16 + p) * 2 + 1];
        rko[base] = v1 * cc - v2 * ss; rko[base + 1] = v1 * ss + v2 * cc;
      } else {
        vo[base] = v1; vo[base + 1] = v2;
      }
    }
  }
}

// gMLP layer 1, BOTH halves, 2048 blocks, untransposed A + pk_fma.
__global__ __launch_bounds__(256) void k_gmlp1(const float* __restrict__ ksrc,
                                               const float* __restrict__ vsrc,
                                               const float* __restrict__ kpos,
                                               const float* __restrict__ vpos,
                                               const float* __restrict__ kw1,
                                               const float* __restrict__ vw1,
                                               float* __restrict__ hb0,
                                               float* __restrict__ hb1) {
  __shared__ float As[64][33];
  __shared__ __align__(16) float Bs[32][68];
  const int half = blockIdx.x >> 10;
  const int bid  = blockIdx.x & 1023;
  const float* kv   = half ? vsrc : ksrc;
  const float* posw = half ? vpos : kpos;
  const float* w1   = half ? vw1  : kw1;
  float* hb         = half ? hb1  : hb0;
  const int xcd = bid & 7;
  const int idx = bid >> 3;            // 0..127
  const int mt  = idx & 7;
  const int nh  = xcd * 16 + (idx >> 3);
  const int n0 = (nh & 15) * 64;
  const int h  = nh >> 4;
  const int m0 = mt * 64;
  const int tid = threadIdx.x;
  const int tx = tid & 15, ty = tid >> 4;
  const float* pw = posw + h * 1024;
  v2f acc2[4][2] = {};
  for (int k0 = 0; k0 < 1024; k0 += 32) {
#pragma unroll
    for (int i = 0; i < 2; ++i) {
      int li = tid + i * 256;
      int mm = li >> 3, c4 = li & 7;
      int row = m0 + mm;
      float4 av = {0.f, 0.f, 0.f, 0.f};
      if (row < 496) {
        int nb = row / 31, bb = row % 31;
        float4 k4 = *reinterpret_cast<const float4*>(
            &kv[((size_t)(nb * 8 + h) * 512 + bb * 16) * 32 + k0 + c4 * 4]);
        float4 p4 = *reinterpret_cast<const float4*>(&pw[k0 + c4 * 4]);
        av.x = k4.x + p4.x; av.y = k4.y + p4.y; av.z = k4.z + p4.z; av.w = k4.w + p4.w;
      }
      As[mm][c4 * 4 + 0] = av.x; As[mm][c4 * 4 + 1] = av.y;
      As[mm][c4 * 4 + 2] = av.z; As[mm][c4 * 4 + 3] = av.w;
    }
#pragma unroll
    for (int i = 0; i < 2; ++i) {
      int li = tid + i * 256;
      int r = li >> 4, c4 = li & 15;
      float4 b4 = *reinterpret_cast<const float4*>(
          &w1[(size_t)h * 1048576 + (size_t)(k0 + r) * 1024 + n0 + c4 * 4]);
      *reinterpret_cast<float4*>(&Bs[r][c4 * 4]) = b4;
    }
    __syncthreads();
#pragma unroll
    for (int kk = 0; kk < 32; ++kk) {
      float a0 = As[ty * 4 + 0][kk], a1 = As[ty * 4 + 1][kk];
      float a2 = As[ty * 4 + 2][kk], a3 = As[ty * 4 + 3][kk];
      float4 b4 = *reinterpret_cast<const float4*>(&Bs[kk][tx * 4]);
      v2f a01 = {a0, a1}, a23 = {a2, a3};
      v2f blo = {b4.x, b4.y}, bhi = {b4.z, b4.w};
      pk_lo(acc2[0][0], a01, blo); pk_lo(acc2[0][1], a01, bhi);
      pk_hi(acc2[1][0], a01, blo); pk_hi(acc2[1][1], a01, bhi);
      pk_lo(acc2[2][0], a23, blo); pk_lo(acc2[2][1], a23, bhi);
      pk_hi(acc2[3][0], a23, blo); pk_hi(acc2[3][1], a23, bhi);
    }
    __syncthreads();
  }
#pragma unroll
  for (int i = 0; i < 4; ++i) {
    int row = m0 + ty * 4 + i;
    if (row < 496) {
      float* dst = &hb[((size_t)h * 496 + row) * 1024 + n0 + tx * 4];
      dst[0] = fmaxf(acc2[i][0].x, 0.f);
      dst[1] = fmaxf(acc2[i][0].y, 0.f);
      dst[2] = fmaxf(acc2[i][1].x, 0.f);
      dst[3] = fmaxf(acc2[i][1].y, 0.f);
    }
  }
}

// gMLP out for BOTH halves in one launch; per-output EXACT ascending-i sum.
__global__ __launch_bounds__(256) void k_g2(const float* __restrict__ hh0,
                                            const float* __restrict__ hh1,
                                            const float* __restrict__ kw2,
                                            const float* __restrict__ vw2,
                                            float* __restrict__ ck,
                                            float* __restrict__ cv) {
  int gid = blockIdx.x * 256 + threadIdx.x;  // 253952 = 2*126976
  int half = gid >= 126976;
  int lid = gid - half * 126976;
  const float* hh = half ? hh1 : hh0;
  const float* w2 = half ? vw2 : kw2;
  float* outp = half ? cv : ck;
  int o = lid & 31;
  int rem = lid >> 5;
  int h = rem / 496, row = rem % 496;
  int nb = row / 31, bb = row % 31;
  const float* hr = hh + (size_t)rem * 1024;
  const float* w2p = w2 + (size_t)h * 32768 + o;
  float s = 0.f;
  for (int i = 0; i < 1024; i += 4) {
    float4 h4 = *reinterpret_cast<const float4*>(&hr[i]);
    s += h4.x * w2p[(size_t)i * 32];
    s += h4.y * w2p[(size_t)(i + 1) * 32];
    s += h4.z * w2p[(size_t)(i + 2) * 32];
    s += h4.w * w2p[(size_t)(i + 3) * 32];
  }
  outp[((size_t)(nb * 8 + h) * 31 + bb) * 32 + o] = s;
}

// compressed attention: 2 blocks per nh (256 total); per-t math identical.
__global__ __launch_bounds__(256) void k_cattn(const float* __restrict__ q,
                                               const float* __restrict__ ck,
                                               const float* __restrict__ cv,
                                               const float* __restrict__ mem_ck,
                                               const float* __restrict__ mem_cv,
                                               const float* __restrict__ gates,
                                               float* __restrict__ obuf,
                                               int* __restrict__ sel) {
  int nh = blockIdx.x >> 1;
  int h = nh & 7, ball = nh >> 3;
  int t = (blockIdx.x & 1) * 256 + threadIdx.x;
  __shared__ float kf[32][33], vf[32][33];
  for (int i = threadIdx.x; i < 1024; i += 256) {
    int j = i >> 5, d = i & 31;
    kf[j][d] = (j == 0) ? mem_ck[h * 32 + d] : ck[((size_t)nh * 31 + j - 1) * 32 + d];
    vf[j][d] = (j == 0) ? mem_cv[h * 32 + d] : cv[((size_t)nh * 31 + j - 1) * 32 + d];
  }
  __syncthreads();
  const float* qp = q + ((size_t)nh * 512 + t) * 32;
  float qr[32];
#pragma unroll
  for (int d = 0; d < 32; ++d) qr[d] = qp[d];
  float sc[32];
  float mx = -INFINITY;
#pragma unroll
  for (int j = 0; j < 32; ++j) {
    float s = -INFINITY;
    bool valid = (j == 0) || (t >= (j - 1) * 16 + 31);
    if (valid) {
      s = 0.f;
      for (int d = 0; d < 32; ++d) s += qr[d] * kf[j][d];
      s *= SCALE_;
    }
    sc[j] = s;
    mx = fmaxf(mx, s);
  }
  float e[32];
  float den = 0.f;
#pragma unroll
  for (int j = 0; j < 32; ++j) { e[j] = expf(sc[j] - mx); den += e[j]; }
  float num[32];
#pragma unroll
  for (int d = 0; d < 32; ++d) num[d] = 0.f;
#pragma unroll
  for (int j = 0; j < 32; ++j) {
    float p = e[j];
    for (int d = 0; d < 32; ++d) num[d] += p * vf[j][d];
  }
  float inv = 1.f / den;
  float g0 = gates[(size_t)(ball * 512 + t) * 24 + h * 3];
  float* op = obuf + (size_t)(ball * 512 + t) * 256 + h * 32;
  for (int d = 0; d < 32; ++d) op[d] = num[d] * inv * g0;

  int s_idx = 0;
  if (t >= 32) {
    int fn = t >> 5;
    float best = -INFINITY;
    for (int f = 0; f < fn; ++f) {
      float im = 0.f;
#pragma unroll
      for (int j = 0; j < 31; ++j) {
        int a = j * 16, b2 = a + 32, fa = f * 32, fb = fa + 32;
        int lo = a > fa ? a : fa;
        int hi = b2 < fb ? b2 : fb;
        if (hi > lo) im += e[j + 1] * (float)(hi - lo) * (1.f / 32.f);
      }
      if (im > best) { best = im; s_idx = f; }
    }
  }
  sel[(size_t)nh * 512 + t] = s_idx;
}

// merged fine + sliding-window attention. obuf order: (c + f*g1) + sw*g2.
__global__ __launch_bounds__(256) void k_fsw(const float* __restrict__ rq,
                                             const float* __restrict__ rk,
                                             const float* __restrict__ v,
                                             const int* __restrict__ sel,
                                             const float* __restrict__ gates,
                                             float* __restrict__ obuf) {
  int b = blockIdx.x, h = blockIdx.y, nb = blockIdx.z;
  int nh = nb * 8 + h;
  __shared__ float rqs[32][33], k2s[64][33], v2s[64][33];
  for (int i = threadIdx.x; i < 1024; i += 256) {
    int r = i >> 5, d = i & 31;
    rqs[r][d] = rq[((size_t)nh * 512 + b * 32 + r) * 32 + d];
  }
  for (int i = threadIdx.x; i < 2048; i += 256) {
    int r = i >> 5, d = i & 31;
    int tk = (b - 1) * 32 + r;
    float kk_ = 0.f, vv_ = 0.f;
    if (tk >= 0) {
      kk_ = rk[((size_t)nh * 512 + tk) * 32 + d];
      vv_ = v[((size_t)nh * 512 + tk) * 32 + d];
    }
    k2s[r][d] = kk_;
    v2s[r][d] = vv_;
  }
  __syncthreads();
  int qi = threadIdx.x >> 3, l = threadIdx.x & 7;
  int t = b * 32 + qi;

  // ---------- fine attention ----------
  int sb = sel[(size_t)nh * 512 + t];
  bool hs = (t >= 32);
  float fo[4];
  {
    float p[8];
    float mx = -INFINITY;
#pragma unroll
    for (int kk2 = 0; kk2 < 8; ++kk2) {
      int kk = l * 8 + kk2;
      float s = -INFINITY;
      if (kk < 32) {
        if (qi >= kk) {
          s = 0.f;
#pragma unroll
          for (int d = 0; d < 32; ++d) s += rqs[qi][d] * k2s[32 + kk][d];
          s *= SCALE_;
        }
      } else if (hs) {
        const float* kp = rk + ((size_t)nh * 512 + sb * 32 + (kk - 32)) * 32;
        s = 0.f;
#pragma unroll
        for (int d = 0; d < 32; ++d) s += rqs[qi][d] * kp[d];
        s *= SCALE_;
      }
      p[kk2] = s;
      mx = fmaxf(mx, s);
    }
#pragma unroll
    for (int off = 4; off; off >>= 1) mx = fmaxf(mx, __shfl_xor(mx, off, 8));
    float sum = 0.f;
#pragma unroll
    for (int kk2 = 0; kk2 < 8; ++kk2) { p[kk2] = expf(p[kk2] - mx); sum += p[kk2]; }
#pragma unroll
    for (int off = 4; off; off >>= 1) sum += __shfl_xor(sum, off, 8);
    float inv = 1.f / sum;
    float acc[32];
#pragma unroll
    for (int d = 0; d < 32; ++d) acc[d] = 0.f;
#pragma unroll
    for (int kk2 = 0; kk2 < 8; ++kk2) {
      int kk = l * 8 + kk2;
      float pwt = p[kk2] * inv;
      if (kk < 32) {
#pragma unroll
        for (int d = 0; d < 32; ++d) acc[d] += pwt * v2s[32 + kk][d];
      } else if (hs) {
        const float* vp = v + ((size_t)nh * 512 + sb * 32 + (kk - 32)) * 32;
#pragma unroll
        for (int d = 0; d < 32; ++d) acc[d] += pwt * vp[d];
      }
    }
#pragma unroll
    for (int off = 4; off; off >>= 1) {
#pragma unroll
      for (int d = 0; d < 32; ++d) acc[d] += __shfl_xor(acc[d], off, 8);
    }
#pragma unroll
    for (int j = 0; j < 4; ++j) fo[j] = acc[l * 4 + j];
  }

  // ---------- sliding window ----------
  float so[4];
  {
    float p[8];
    float mx = -INFINITY;
#pragma unroll
    for (int kk2 = 0; kk2 < 8; ++kk2) {
      int kk = l * 8 + kk2;
      bool valid = (kk > qi) && (kk <= qi + 32) && ((b > 0) || (kk >= 32));
      float s = -INFINITY;
      if (valid) {
        s = 0.f;
#pragma unroll
        for (int d = 0; d < 32; ++d) s += rqs[qi][d] * k2s[kk][d];
        s *= SCALE_;
      }
      p[kk2] = s;
      mx = fmaxf(mx, s);
    }
#pragma unroll
    for (int off = 4; off; off >>= 1) mx = fmaxf(mx, __shfl_xor(mx, off, 8));
    float sum = 0.f;
#pragma unroll
    for (int kk2 = 0; kk2 < 8; ++kk2) { p[kk2] = expf(p[kk2] - mx); sum += p[kk2]; }
#pragma unroll
    for (int off = 4; off; off >>= 1) sum += __shfl_xor(sum, off, 8);
    float inv = 1.f / sum;
    float acc[32];
#pragma unroll
    for (int d = 0; d < 32; ++d) acc[d] = 0.f;
#pragma unroll
    for (int kk2 = 0; kk2 < 8; ++kk2) {
      int kk = l * 8 + kk2;
      float pwt = p[kk2] * inv;
#pragma unroll
      for (int d = 0; d < 32; ++d) acc[d] += pwt * v2s[kk][d];
    }
#pragma unroll
    for (int off = 4; off; off >>= 1) {
#pragma unroll
      for (int d = 0; d < 32; ++d) acc[d] += __shfl_xor(acc[d], off, 8);
    }
#pragma unroll
    for (int j = 0; j < 4; ++j) so[j] = acc[l * 4 + j];
  }

  float g1 = gates[(size_t)(nb * 512 + t) * 24 + h * 3 + 1];
  float g2 = gates[(size_t)(nb * 512 + t) * 24 + h * 3 + 2];
  float* op = obuf + (size_t)(nb * 512 + t) * 256 + h * 32;
#pragma unroll
  for (int j = 0; j < 4; ++j) {
    float cur = op[l * 4 + j];
    cur += fo[j] * g1;
    cur += so[j] * g2;
    op[l * 4 + j] = cur;
  }
}

// final projection: 64x64, untransposed A + pk_fma, XCD swizzle.
__global__ __launch_bounds__(256) void k_out(const float* __restrict__ A,
                                             const float* __restrict__ B,
                                             float* __restrict__ C) {
  __shared__ float As[64][33];
  __shared__ __align__(16) float Bs[32][68];
  const int bid = blockIdx.x;            // 512 = 8 xcd * 16 m * 4 n
  const int xcd = bid & 7;
  const int idx = bid >> 3;
  const int m0 = (xcd * 16 + (idx & 15)) * 64;
  const int n0 = (idx >> 4) * 64;
  const int tid = threadIdx.x;
  const int tx = tid & 15, ty = tid >> 4;
  v2f acc2[4][2] = {};
  for (int k0 = 0; k0 < 256; k0 += 32) {
#pragma unroll
    for (int i = 0; i < 2; ++i) {
      int li = tid + i * 256;
      int mm = li >> 3, c4 = li & 7;
      float4 a4 = *reinterpret_cast<const float4*>(&A[(size_t)(m0 + mm) * 256 + k0 + c4 * 4]);
      As[mm][c4 * 4 + 0] = a4.x; As[mm][c4 * 4 + 1] = a4.y;
      As[mm][c4 * 4 + 2] = a4.z; As[mm][c4 * 4 + 3] = a4.w;
    }
#pragma unroll
    for (int i = 0; i < 2; ++i) {
      int li = tid + i * 256;
      int r = li >> 4, c4 = li & 15;
      float4 b4 = *reinterpret_cast<const float4*>(&B[(size_t)(k0 + r) * 256 + n0 + c4 * 4]);
      *reinterpret_cast<float4*>(&Bs[r][c4 * 4]) = b4;
    }
    __syncthreads();
#pragma unroll
    for (int kk = 0; kk < 32; ++kk) {
      float a0 = As[ty * 4 + 0][kk], a1 = As[ty * 4 + 1][kk];
      float a2 = As[ty * 4 + 2][kk], a3 = As[ty * 4 + 3][kk];
      float4 b4 = *reinterpret_cast<const float4*>(&Bs[kk][tx * 4]);
      v2f a01 = {a0, a1}, a23 = {a2, a3};
      v2f blo = {b4.x, b4.y}, bhi = {b4.z, b4.w};
      pk_lo(acc2[0][0], a01, blo); pk_lo(acc2[0][1], a01, bhi);
      pk_hi(acc2[1][0], a01, blo); pk_hi(acc2[1][1], a01, bhi);
      pk_lo(acc2[2][0], a23, blo); pk_lo(acc2[2][1], a23, bhi);
      pk_hi(acc2[3][0], a23, blo); pk_hi(acc2[3][1], a23, bhi);
    }
    __syncthreads();
  }
#pragma unroll
  for (int i = 0; i < 4; ++i) {
    int row = m0 + ty * 4 + i;
    float* dst = &C[(size_t)row * 256 + n0 + tx * 4];
    dst[0] = acc2[i][0].x;
    dst[1] = acc2[i][0].y;
    dst[2] = acc2[i][1].x;
    dst[3] = acc2[i][1].y;
  }
}

extern "C" void kernel_launch(void* const* d_in, const int* in_sizes, int n_in,
                              void* d_out, int out_size, void* d_ws, size_t ws_size,
                              hipStream_t stream) {
  const float* x      = (const float*)d_in[0];
  const float* pos    = (const float*)d_in[1];
  const float* Wpe    = (const float*)d_in[2];
  const float* bpe    = (const float*)d_in[3];
  const float* rms_w  = (const float*)d_in[4];
  const float* Wqkv   = (const float*)d_in[5];
  const float* kpos   = (const float*)d_in[6];
  const float* vpos   = (const float*)d_in[7];
  const float* kw1    = (const float*)d_in[8];
  const float* kw2    = (const float*)d_in[9];
  const float* vw1    = (const float*)d_in[10];
  const float* vw2    = (const float*)d_in[11];
  const float* mem_ck = (const float*)d_in[12];
  const float* mem_cv = (const float*)d_in[13];
  const float* Wg     = (const float*)d_in[14];
  const float* Wo     = (const float*)d_in[15];
  float* out = (float*)d_out;

  float* ws = (float*)d_ws;
  const size_t TOK = 2097152;  // 8192*256
  float* q     = ws;
  float* k     = ws + TOK;
  float* v     = ws + 2 * TOK;
  float* rq    = ws + 3 * TOK;
  float* rk    = ws + 4 * TOK;
  float* hn    = ws + 5 * TOK;
  float* obuf  = ws + 6 * TOK;
  float* hh    = ws + 7 * TOK;       // 4,063,232
  float* hh2   = hn;                 // aliases hn+obuf span (hn dead after k_qkv)
  float* ck    = hh + 4063232;
  float* cv    = ck + 126976;
  float* gates = cv + 126976;
  float* rope  = gates + 196608;
  float* pm    = rope + 16384;
  int*   sel   = (int*)(pm + 64);

  k_pre<<<48, 256, 0, stream>>>(pos, rope, pm);
  k_hn<<<256, 256, 0, stream>>>(x, pos, pm, Wpe, bpe, rms_w, Wg, hn, gates);
  k_qkv<<<1536, 256, 0, stream>>>(hn, Wqkv, rope, q, k, v, rq, rk);
  k_gmlp1<<<2048, 256, 0, stream>>>(k, v, kpos, vpos, kw1, vw1, hh, hh2);
  k_g2<<<992, 256, 0, stream>>>(hh, hh2, kw2, vw2, ck, cv);
  k_cattn<<<256, 256, 0, stream>>>(q, ck, cv, mem_ck, mem_cv, gates, obuf, sel);
  k_fsw<<<dim3(16, 8, 16), 256, 0, stream>>>(rq, rk, v, sel, gates, obuf);
  k_out<<<512, 256, 0, stream>>>(obuf, Wo, out);
}

// Round 20
// 510.519 us; speedup vs baseline: 1.1318x; 1.1318x over previous
//
#include <hip/hip_runtime.h>
#include <hip/hip_bf16.h>
#include <math.h>

#define SCALE_ 0.17677669529663687f
typedef float v2f __attribute__((ext_vector_type(2)));

// two independent IEEE FMAs per instr; op_sel broadcasts a.lo / a.hi to both
// halves. Per-element order and rounding identical to scalar => bit-exact.
__device__ __forceinline__ void pk_lo(v2f& acc, v2f a, v2f b) {
  asm("v_pk_fma_f32 %0, %1, %2, %0 op_sel:[0,0,0] op_sel_hi:[0,1,1]"
      : "+v"(acc) : "v"(a), "v"(b));
}
__device__ __forceinline__ void pk_hi(v2f& acc, v2f a, v2f b) {
  asm("v_pk_fma_f32 %0, %1, %2, %0 op_sel:[1,0,0] op_sel_hi:[1,1,1]"
      : "+v"(acc) : "v"(a), "v"(b));
}

// fused: rope table (blocks 0-31) + per-ball pos mean (blocks 32-47)
__global__ __launch_bounds__(256) void k_pre(const float* __restrict__ pos,
                                             float* __restrict__ rope,
                                             float* __restrict__ pm) {
  __shared__ float ps[1536];
  if (blockIdx.x < 32) {
    int i = blockIdx.x * 256 + threadIdx.x;  // 8192
    int t = i >> 4, j = i & 15;
    float inv = powf(10000.f, -(float)j / 16.f);
    float ang = (float)t * inv;
    rope[2 * i]     = cosf(ang);
    rope[2 * i + 1] = sinf(ang);
  } else {
    int ball = blockIdx.x - 32;
    for (int i = threadIdx.x; i < 1536; i += 256) ps[i] = pos[(size_t)ball * 1536 + i];
    __syncthreads();
    if (threadIdx.x < 3) {
      int c = threadIdx.x;
      float s = 0.f;
      for (int t = 0; t < 512; ++t) s += ps[t * 3 + c];  // EXACT t-ascending (sel-sensitive)
      pm[ball * 3 + c] = s * (1.f / 512.f);
    }
  }
}

// hn + fused gates. EXACT sequential ss sum per token (sel-sensitive).
__global__ __launch_bounds__(256) void k_hn(const float* __restrict__ x,
                                            const float* __restrict__ pos,
                                            const float* __restrict__ pm,
                                            const float* __restrict__ Wpe,
                                            const float* __restrict__ bpe,
                                            const float* __restrict__ rmsw,
                                            const float* __restrict__ Wg,
                                            float* __restrict__ hn,
                                            float* __restrict__ gates) {
  __shared__ float hx[32][257];
  __shared__ float rr[32][3];
  __shared__ float invs[32];
  int tb = blockIdx.x * 32;  // 256 blocks
  if (threadIdx.x < 96) {
    int tok = threadIdx.x / 3, c = threadIdx.x % 3;
    rr[tok][c] = pos[(size_t)(tb + tok) * 3 + c] - pm[((tb + tok) >> 9) * 3 + c];
  }
  __syncthreads();
  for (int i = threadIdx.x; i < 8192; i += 256) {
    int tok = i >> 8, d = i & 255;
    float h = x[(size_t)(tb + tok) * 256 + d] + rr[tok][0] * Wpe[d] + rr[tok][1] * Wpe[256 + d]
            + rr[tok][2] * Wpe[512 + d] + bpe[d];
    hx[tok][d] = h;
  }
  __syncthreads();
  if (threadIdx.x < 32) {
    int tok = threadIdx.x;
    float ss = 0.f;
    for (int d = 0; d < 256; ++d) { float h = hx[tok][d]; ss += h * h; }
    invs[tok] = 1.f / sqrtf(ss * (1.f / 256.f) + 1e-6f);
  }
  __syncthreads();
  for (int i = threadIdx.x; i < 8192; i += 256) {
    int tok = i >> 8, d = i & 255;
    float hv = hx[tok][d] * invs[tok] * rmsw[d];
    hn[(size_t)(tb + tok) * 256 + d] = hv;
    hx[tok][d] = hv;
  }
  __syncthreads();
  for (int g = threadIdx.x; g < 768; g += 256) {
    int tok = g / 24, j = g % 24;
    float s = 0.f;
    for (int d = 0; d < 256; ++d) s += hx[tok][d] * Wg[d * 24 + j];
    gates[(size_t)(tb + tok) * 24 + j] = 1.f / (1.f + expf(-s));
  }
}

// qkv = hn @ Wqkv, 64x64, transposed As[32][68], pk_fma, b128 reads, fused RoPE.
__global__ __launch_bounds__(256) void k_qkv(const float* __restrict__ A,
                                             const float* __restrict__ B,
                                             const float* __restrict__ rope,
                                             float* __restrict__ qo,
                                             float* __restrict__ ko,
                                             float* __restrict__ vo,
                                             float* __restrict__ rqo,
                                             float* __restrict__ rko) {
  __shared__ __align__(16) float As[32][68];
  __shared__ __align__(16) float Bs[32][68];
  const int bid = blockIdx.x;            // 1536 = 8 xcd * 16 m * 12 n
  const int xcd = bid & 7;
  const int idx = bid >> 3;
  const int m0 = (xcd * 16 + (idx & 15)) * 64;
  const int n0 = (idx >> 4) * 64;
  const int tid = threadIdx.x;
  const int tx = tid & 15, ty = tid >> 4;
  v2f acc2[4][2] = {};
  for (int k0 = 0; k0 < 256; k0 += 32) {
#pragma unroll
    for (int i = 0; i < 2; ++i) {
      int li = tid + i * 256;
      int mm = li >> 3, c4 = li & 7;
      float4 a4 = *reinterpret_cast<const float4*>(&A[(size_t)(m0 + mm) * 256 + k0 + c4 * 4]);
      As[c4 * 4 + 0][mm] = a4.x; As[c4 * 4 + 1][mm] = a4.y;
      As[c4 * 4 + 2][mm] = a4.z; As[c4 * 4 + 3][mm] = a4.w;
    }
#pragma unroll
    for (int i = 0; i < 2; ++i) {
      int li = tid + i * 256;
      int r = li >> 4, c4 = li & 15;
      float4 b4 = *reinterpret_cast<const float4*>(&B[(size_t)(k0 + r) * 768 + n0 + c4 * 4]);
      *reinterpret_cast<float4*>(&Bs[r][c4 * 4]) = b4;
    }
    __syncthreads();
#pragma unroll
    for (int kk = 0; kk < 32; ++kk) {
      float4 a4 = *reinterpret_cast<const float4*>(&As[kk][ty * 4]);
      float4 b4 = *reinterpret_cast<const float4*>(&Bs[kk][tx * 4]);
      v2f a01 = {a4.x, a4.y}, a23 = {a4.z, a4.w};
      v2f blo = {b4.x, b4.y}, bhi = {b4.z, b4.w};
      pk_lo(acc2[0][0], a01, blo); pk_lo(acc2[0][1], a01, bhi);
      pk_hi(acc2[1][0], a01, blo); pk_hi(acc2[1][1], a01, bhi);
      pk_lo(acc2[2][0], a23, blo); pk_lo(acc2[2][1], a23, bhi);
      pk_hi(acc2[3][0], a23, blo); pk_hi(acc2[3][1], a23, bhi);
    }
    __syncthreads();
  }
#pragma unroll
  for (int i = 0; i < 4; ++i) {
    int row = m0 + ty * 4 + i;
    int nb = row >> 9, t = row & 511;
#pragma unroll
    for (int j = 0; j < 4; j += 2) {
      int col = n0 + tx * 4 + j;
      int which = col >> 8, cj = col & 255;
      int h = cj >> 5, d = cj & 31;
      float v1 = (j == 0) ? acc2[i][0].x : acc2[i][1].x;
      float v2 = (j == 0) ? acc2[i][0].y : acc2[i][1].y;
      size_t base = ((size_t)(nb * 8 + h) * 512 + t) * 32 + d;
      if (which == 0) {
        qo[base] = v1; qo[base + 1] = v2;
        int p = d >> 1;
        float cc = rope[(t * 16 + p) * 2], ss = rope[(t * 16 + p) * 2 + 1];
        rqo[base] = v1 * cc - v2 * ss; rqo[base + 1] = v1 * ss + v2 * cc;
      } else if (which == 1) {
        ko[base] = v1; ko[base + 1] = v2;
        int p = d >> 1;
        float cc = rope[(t * 16 + p) * 2], ss = rope[(t * 16 + p) * 2 + 1];
        rko[base] = v1 * cc - v2 * ss; rko[base + 1] = v1 * ss + v2 * cc;
      } else {
        vo[base] = v1; vo[base + 1] = v2;
      }
    }
  }
}

// gMLP layer 1, BOTH halves, 1024 blocks: 128x64 tile, 8x4 acc, pk_fma.
// A staged transposed pad 130 (mod 32 == 2 => 2-way-free writes; 520B rows
// are 8B-aligned => b64 frag reads). K ascending => bit-exact.
__global__ __launch_bounds__(256) void k_gmlp1(const float* __restrict__ ksrc,
                                               const float* __restrict__ vsrc,
                                               const float* __restrict__ kpos,
                                               const float* __restrict__ vpos,
                                               const float* __restrict__ kw1,
                                               const float* __restrict__ vw1,
                                               float* __restrict__ hb0,
                                               float* __restrict__ hb1) {
  __shared__ __align__(16) float As[32][130];
  __shared__ __align__(16) float Bs[32][68];
  const int half = blockIdx.x >> 9;      // 0:k, 1:v
  const int bid  = blockIdx.x & 511;
  const float* kv   = half ? vsrc : ksrc;
  const float* posw = half ? vpos : kpos;
  const float* w1   = half ? vw1  : kw1;
  float* hb         = half ? hb1  : hb0;
  const int xcd = bid & 7;
  const int idx = bid >> 3;            // 0..63
  const int mt  = idx & 3;             // 4 m-tiles of 128
  const int nh  = xcd * 16 + (idx >> 2);  // 0..127
  const int n0 = (nh & 15) * 64;
  const int h  = nh >> 4;
  const int m0 = mt * 128;
  const int tid = threadIdx.x;
  const int tx = tid & 15, ty = tid >> 4;  // tx: 4 cols, ty: 8 rows
  const float* pw = posw + h * 1024;
  v2f acc2[8][2] = {};
  for (int k0 = 0; k0 < 1024; k0 += 32) {
#pragma unroll
    for (int i = 0; i < 4; ++i) {
      int li = tid + i * 256;
      int mm = li >> 3, c4 = li & 7;
      int row = m0 + mm;
      float4 av = {0.f, 0.f, 0.f, 0.f};
      if (row < 496) {
        int nb = row / 31, bb = row % 31;
        float4 k4 = *reinterpret_cast<const float4*>(
            &kv[((size_t)(nb * 8 + h) * 512 + bb * 16) * 32 + k0 + c4 * 4]);
        float4 p4 = *reinterpret_cast<const float4*>(&pw[k0 + c4 * 4]);
        av.x = k4.x + p4.x; av.y = k4.y + p4.y; av.z = k4.z + p4.z; av.w = k4.w + p4.w;
      }
      As[c4 * 4 + 0][mm] = av.x; As[c4 * 4 + 1][mm] = av.y;
      As[c4 * 4 + 2][mm] = av.z; As[c4 * 4 + 3][mm] = av.w;
    }
#pragma unroll
    for (int i = 0; i < 2; ++i) {
      int li = tid + i * 256;
      int r = li >> 4, c4 = li & 15;
      float4 b4 = *reinterpret_cast<const float4*>(
          &w1[(size_t)h * 1048576 + (size_t)(k0 + r) * 1024 + n0 + c4 * 4]);
      *reinterpret_cast<float4*>(&Bs[r][c4 * 4]) = b4;
    }
    __syncthreads();
#pragma unroll
    for (int kk = 0; kk < 32; ++kk) {
      v2f a01 = *reinterpret_cast<const v2f*>(&As[kk][ty * 8]);
      v2f a23 = *reinterpret_cast<const v2f*>(&As[kk][ty * 8 + 2]);
      v2f a45 = *reinterpret_cast<const v2f*>(&As[kk][ty * 8 + 4]);
      v2f a67 = *reinterpret_cast<const v2f*>(&As[kk][ty * 8 + 6]);
      float4 b4 = *reinterpret_cast<const float4*>(&Bs[kk][tx * 4]);
      v2f blo = {b4.x, b4.y}, bhi = {b4.z, b4.w};
      pk_lo(acc2[0][0], a01, blo); pk_lo(acc2[0][1], a01, bhi);
      pk_hi(acc2[1][0], a01, blo); pk_hi(acc2[1][1], a01, bhi);
      pk_lo(acc2[2][0], a23, blo); pk_lo(acc2[2][1], a23, bhi);
      pk_hi(acc2[3][0], a23, blo); pk_hi(acc2[3][1], a23, bhi);
      pk_lo(acc2[4][0], a45, blo); pk_lo(acc2[4][1], a45, bhi);
      pk_hi(acc2[5][0], a45, blo); pk_hi(acc2[5][1], a45, bhi);
      pk_lo(acc2[6][0], a67, blo); pk_lo(acc2[6][1], a67, bhi);
      pk_hi(acc2[7][0], a67, blo); pk_hi(acc2[7][1], a67, bhi);
    }
    __syncthreads();
  }
#pragma unroll
  for (int i = 0; i < 8; ++i) {
    int row = m0 + ty * 8 + i;
    if (row < 496) {
      float* dst = &hb[((size_t)h * 496 + row) * 1024 + n0 + tx * 4];
      dst[0] = fmaxf(acc2[i][0].x, 0.f);
      dst[1] = fmaxf(acc2[i][0].y, 0.f);
      dst[2] = fmaxf(acc2[i][1].x, 0.f);
      dst[3] = fmaxf(acc2[i][1].y, 0.f);
    }
  }
}

// gMLP out for BOTH halves in one launch; per-output EXACT ascending-i sum.
__global__ __launch_bounds__(256) void k_g2(const float* __restrict__ hh0,
                                            const float* __restrict__ hh1,
                                            const float* __restrict__ kw2,
                                            const float* __restrict__ vw2,
                                            float* __restrict__ ck,
                                            float* __restrict__ cv) {
  int gid = blockIdx.x * 256 + threadIdx.x;  // 253952 = 2*126976
  int half = gid >= 126976;
  int lid = gid - half * 126976;
  const float* hh = half ? hh1 : hh0;
  const float* w2 = half ? vw2 : kw2;
  float* outp = half ? cv : ck;
  int o = lid & 31;
  int rem = lid >> 5;
  int h = rem / 496, row = rem % 496;
  int nb = row / 31, bb = row % 31;
  const float* hr = hh + (size_t)rem * 1024;
  const float* w2p = w2 + (size_t)h * 32768 + o;
  float s = 0.f;
  for (int i = 0; i < 1024; i += 4) {
    float4 h4 = *reinterpret_cast<const float4*>(&hr[i]);
    s += h4.x * w2p[(size_t)i * 32];
    s += h4.y * w2p[(size_t)(i + 1) * 32];
    s += h4.z * w2p[(size_t)(i + 2) * 32];
    s += h4.w * w2p[(size_t)(i + 3) * 32];
  }
  outp[((size_t)(nb * 8 + h) * 31 + bb) * 32 + o] = s;
}

// compressed attention: 2 blocks per nh (256 total); per-t math identical.
__global__ __launch_bounds__(256) void k_cattn(const float* __restrict__ q,
                                               const float* __restrict__ ck,
                                               const float* __restrict__ cv,
                                               const float* __restrict__ mem_ck,
                                               const float* __restrict__ mem_cv,
                                               const float* __restrict__ gates,
                                               float* __restrict__ obuf,
                                               int* __restrict__ sel) {
  int nh = blockIdx.x >> 1;
  int h = nh & 7, ball = nh >> 3;
  int t = (blockIdx.x & 1) * 256 + threadIdx.x;
  __shared__ float kf[32][33], vf[32][33];
  for (int i = threadIdx.x; i < 1024; i += 256) {
    int j = i >> 5, d = i & 31;
    kf[j][d] = (j == 0) ? mem_ck[h * 32 + d] : ck[((size_t)nh * 31 + j - 1) * 32 + d];
    vf[j][d] = (j == 0) ? mem_cv[h * 32 + d] : cv[((size_t)nh * 31 + j - 1) * 32 + d];
  }
  __syncthreads();
  const float* qp = q + ((size_t)nh * 512 + t) * 32;
  float qr[32];
#pragma unroll
  for (int d = 0; d < 32; ++d) qr[d] = qp[d];
  float sc[32];
  float mx = -INFINITY;
#pragma unroll
  for (int j = 0; j < 32; ++j) {
    float s = -INFINITY;
    bool valid = (j == 0) || (t >= (j - 1) * 16 + 31);
    if (valid) {
      s = 0.f;
      for (int d = 0; d < 32; ++d) s += qr[d] * kf[j][d];
      s *= SCALE_;
    }
    sc[j] = s;
    mx = fmaxf(mx, s);
  }
  float e[32];
  float den = 0.f;
#pragma unroll
  for (int j = 0; j < 32; ++j) { e[j] = expf(sc[j] - mx); den += e[j]; }
  float num[32];
#pragma unroll
  for (int d = 0; d < 32; ++d) num[d] = 0.f;
#pragma unroll
  for (int j = 0; j < 32; ++j) {
    float p = e[j];
    for (int d = 0; d < 32; ++d) num[d] += p * vf[j][d];
  }
  float inv = 1.f / den;
  float g0 = gates[(size_t)(ball * 512 + t) * 24 + h * 3];
  float* op = obuf + (size_t)(ball * 512 + t) * 256 + h * 32;
  for (int d = 0; d < 32; ++d) op[d] = num[d] * inv * g0;

  int s_idx = 0;
  if (t >= 32) {
    int fn = t >> 5;
    float best = -INFINITY;
    for (int f = 0; f < fn; ++f) {
      float im = 0.f;
#pragma unroll
      for (int j = 0; j < 31; ++j) {
        int a = j * 16, b2 = a + 32, fa = f * 32, fb = fa + 32;
        int lo = a > fa ? a : fa;
        int hi = b2 < fb ? b2 : fb;
        if (hi > lo) im += e[j + 1] * (float)(hi - lo) * (1.f / 32.f);
      }
      if (im > best) { best = im; s_idx = f; }
    }
  }
  sel[(size_t)nh * 512 + t] = s_idx;
}

// merged fine + sliding-window attention. obuf order: (c + f*g1) + sw*g2.
__global__ __launch_bounds__(256) void k_fsw(const float* __restrict__ rq,
                                             const float* __restrict__ rk,
                                             const float* __restrict__ v,
                                             const int* __restrict__ sel,
                                             const float* __restrict__ gates,
                                             float* __restrict__ obuf) {
  int b = blockIdx.x, h = blockIdx.y, nb = blockIdx.z;
  int nh = nb * 8 + h;
  __shared__ float rqs[32][33], k2s[64][33], v2s[64][33];
  for (int i = threadIdx.x; i < 1024; i += 256) {
    int r = i >> 5, d = i & 31;
    rqs[r][d] = rq[((size_t)nh * 512 + b * 32 + r) * 32 + d];
  }
  for (int i = threadIdx.x; i < 2048; i += 256) {
    int r = i >> 5, d = i & 31;
    int tk = (b - 1) * 32 + r;
    float kk_ = 0.f, vv_ = 0.f;
    if (tk >= 0) {
      kk_ = rk[((size_t)nh * 512 + tk) * 32 + d];
      vv_ = v[((size_t)nh * 512 + tk) * 32 + d];
    }
    k2s[r][d] = kk_;
    v2s[r][d] = vv_;
  }
  __syncthreads();
  int qi = threadIdx.x >> 3, l = threadIdx.x & 7;
  int t = b * 32 + qi;

  // ---------- fine attention ----------
  int sb = sel[(size_t)nh * 512 + t];
  bool hs = (t >= 32);
  float fo[4];
  {
    float p[8];
    float mx = -INFINITY;
#pragma unroll
    for (int kk2 = 0; kk2 < 8; ++kk2) {
      int kk = l * 8 + kk2;
      float s = -INFINITY;
      if (kk < 32) {
        if (qi >= kk) {
          s = 0.f;
#pragma unroll
          for (int d = 0; d < 32; ++d) s += rqs[qi][d] * k2s[32 + kk][d];
          s *= SCALE_;
        }
      } else if (hs) {
        const float* kp = rk + ((size_t)nh * 512 + sb * 32 + (kk - 32)) * 32;
        s = 0.f;
#pragma unroll
        for (int d = 0; d < 32; ++d) s += rqs[qi][d] * kp[d];
        s *= SCALE_;
      }
      p[kk2] = s;
      mx = fmaxf(mx, s);
    }
#pragma unroll
    for (int off = 4; off; off >>= 1) mx = fmaxf(mx, __shfl_xor(mx, off, 8));
    float sum = 0.f;
#pragma unroll
    for (int kk2 = 0; kk2 < 8; ++kk2) { p[kk2] = expf(p[kk2] - mx); sum += p[kk2]; }
#pragma unroll
    for (int off = 4; off; off >>= 1) sum += __shfl_xor(sum, off, 8);
    float inv = 1.f / sum;
    float acc[32];
#pragma unroll
    for (int d = 0; d < 32; ++d) acc[d] = 0.f;
#pragma unroll
    for (int kk2 = 0; kk2 < 8; ++kk2) {
      int kk = l * 8 + kk2;
      float pwt = p[kk2] * inv;
      if (kk < 32) {
#pragma unroll
        for (int d = 0; d < 32; ++d) acc[d] += pwt * v2s[32 + kk][d];
      } else if (hs) {
        const float* vp = v + ((size_t)nh * 512 + sb * 32 + (kk - 32)) * 32;
#pragma unroll
        for (int d = 0; d < 32; ++d) acc[d] += pwt * vp[d];
      }
    }
#pragma unroll
    for (int off = 4; off; off >>= 1) {
#pragma unroll
      for (int d = 0; d < 32; ++d) acc[d] += __shfl_xor(acc[d], off, 8);
    }
#pragma unroll
    for (int j = 0; j < 4; ++j) fo[j] = acc[l * 4 + j];
  }

  // ---------- sliding window ----------
  float so[4];
  {
    float p[8];
    float mx = -INFINITY;
#pragma unroll
    for (int kk2 = 0; kk2 < 8; ++kk2) {
      int kk = l * 8 + kk2;
      bool valid = (kk > qi) && (kk <= qi + 32) && ((b > 0) || (kk >= 32));
      float s = -INFINITY;
      if (valid) {
        s = 0.f;
#pragma unroll
        for (int d = 0; d < 32; ++d) s += rqs[qi][d] * k2s[kk][d];
        s *= SCALE_;
      }
      p[kk2] = s;
      mx = fmaxf(mx, s);
    }
#pragma unroll
    for (int off = 4; off; off >>= 1) mx = fmaxf(mx, __shfl_xor(mx, off, 8));
    float sum = 0.f;
#pragma unroll
    for (int kk2 = 0; kk2 < 8; ++kk2) { p[kk2] = expf(p[kk2] - mx); sum += p[kk2]; }
#pragma unroll
    for (int off = 4; off; off >>= 1) sum += __shfl_xor(sum, off, 8);
    float inv = 1.f / sum;
    float acc[32];
#pragma unroll
    for (int d = 0; d < 32; ++d) acc[d] = 0.f;
#pragma unroll
    for (int kk2 = 0; kk2 < 8; ++kk2) {
      int kk = l * 8 + kk2;
      float pwt = p[kk2] * inv;
#pragma unroll
      for (int d = 0; d < 32; ++d) acc[d] += pwt * v2s[kk][d];
    }
#pragma unroll
    for (int off = 4; off; off >>= 1) {
#pragma unroll
      for (int d = 0; d < 32; ++d) acc[d] += __shfl_xor(acc[d], off, 8);
    }
#pragma unroll
    for (int j = 0; j < 4; ++j) so[j] = acc[l * 4 + j];
  }

  float g1 = gates[(size_t)(nb * 512 + t) * 24 + h * 3 + 1];
  float g2 = gates[(size_t)(nb * 512 + t) * 24 + h * 3 + 2];
  float* op = obuf + (size_t)(nb * 512 + t) * 256 + h * 32;
#pragma unroll
  for (int j = 0; j < 4; ++j) {
    float cur = op[l * 4 + j];
    cur += fo[j] * g1;
    cur += so[j] * g2;
    op[l * 4 + j] = cur;
  }
}

// final projection: 64x64, transposed As[32][68], pk_fma, XCD swizzle.
__global__ __launch_bounds__(256) void k_out(const float* __restrict__ A,
                                             const float* __restrict__ B,
                                             float* __restrict__ C) {
  __shared__ __align__(16) float As[32][68];
  __shared__ __align__(16) float Bs[32][68];
  const int bid = blockIdx.x;            // 512 = 8 xcd * 16 m * 4 n
  const int xcd = bid & 7;
  const int idx = bid >> 3;
  const int m0 = (xcd * 16 + (idx & 15)) * 64;
  const int n0 = (idx >> 4) * 64;
  const int tid = threadIdx.x;
  const int tx = tid & 15, ty = tid >> 4;
  v2f acc2[4][2] = {};
  for (int k0 = 0; k0 < 256; k0 += 32) {
#pragma unroll
    for (int i = 0; i < 2; ++i) {
      int li = tid + i * 256;
      int mm = li >> 3, c4 = li & 7;
      float4 a4 = *reinterpret_cast<const float4*>(&A[(size_t)(m0 + mm) * 256 + k0 + c4 * 4]);
      As[c4 * 4 + 0][mm] = a4.x; As[c4 * 4 + 1][mm] = a4.y;
      As[c4 * 4 + 2][mm] = a4.z; As[c4 * 4 + 3][mm] = a4.w;
    }
#pragma unroll
    for (int i = 0; i < 2; ++i) {
      int li = tid + i * 256;
      int r = li >> 4, c4 = li & 15;
      float4 b4 = *reinterpret_cast<const float4*>(&B[(size_t)(k0 + r) * 256 + n0 + c4 * 4]);
      *reinterpret_cast<float4*>(&Bs[r][c4 * 4]) = b4;
    }
    __syncthreads();
#pragma unroll
    for (int kk = 0; kk < 32; ++kk) {
      float4 a4 = *reinterpret_cast<const float4*>(&As[kk][ty * 4]);
      float4 b4 = *reinterpret_cast<const float4*>(&Bs[kk][tx * 4]);
      v2f a01 = {a4.x, a4.y}, a23 = {a4.z, a4.w};
      v2f blo = {b4.x, b4.y}, bhi = {b4.z, b4.w};
      pk_lo(acc2[0][0], a01, blo); pk_lo(acc2[0][1], a01, bhi);
      pk_hi(acc2[1][0], a01, blo); pk_hi(acc2[1][1], a01, bhi);
      pk_lo(acc2[2][0], a23, blo); pk_lo(acc2[2][1], a23, bhi);
      pk_hi(acc2[3][0], a23, blo); pk_hi(acc2[3][1], a23, bhi);
    }
    __syncthreads();
  }
#pragma unroll
  for (int i = 0; i < 4; ++i) {
    int row = m0 + ty * 4 + i;
    float* dst = &C[(size_t)row * 256 + n0 + tx * 4];
    dst[0] = acc2[i][0].x;
    dst[1] = acc2[i][0].y;
    dst[2] = acc2[i][1].x;
    dst[3] = acc2[i][1].y;
  }
}

extern "C" void kernel_launch(void* const* d_in, const int* in_sizes, int n_in,
                              void* d_out, int out_size, void* d_ws, size_t ws_size,
                              hipStream_t stream) {
  const float* x      = (const float*)d_in[0];
  const float* pos    = (const float*)d_in[1];
  const float* Wpe    = (const float*)d_in[2];
  const float* bpe    = (const float*)d_in[3];
  const float* rms_w  = (const float*)d_in[4];
  const float* Wqkv   = (const float*)d_in[5];
  const float* kpos   = (const float*)d_in[6];
  const float* vpos   = (const float*)d_in[7];
  const float* kw1    = (const float*)d_in[8];
  const float* kw2    = (const float*)d_in[9];
  const float* vw1    = (const float*)d_in[10];
  const float* vw2    = (const float*)d_in[11];
  const float* mem_ck = (const float*)d_in[12];
  const float* mem_cv = (const float*)d_in[13];
  const float* Wg     = (const float*)d_in[14];
  const float* Wo     = (const float*)d_in[15];
  float* out = (float*)d_out;

  float* ws = (float*)d_ws;
  const size_t TOK = 2097152;  // 8192*256
  float* q     = ws;
  float* k     = ws + TOK;
  float* v     = ws + 2 * TOK;
  float* rq    = ws + 3 * TOK;
  float* rk    = ws + 4 * TOK;
  float* hn    = ws + 5 * TOK;
  float* obuf  = ws + 6 * TOK;
  float* hh    = ws + 7 * TOK;       // 4,063,232
  float* hh2   = hn;                 // aliases hn+obuf span (hn dead after k_qkv)
  float* ck    = hh + 4063232;
  float* cv    = ck + 126976;
  float* gates = cv + 126976;
  float* rope  = gates + 196608;
  float* pm    = rope + 16384;
  int*   sel   = (int*)(pm + 64);

  k_pre<<<48, 256, 0, stream>>>(pos, rope, pm);
  k_hn<<<256, 256, 0, stream>>>(x, pos, pm, Wpe, bpe, rms_w, Wg, hn, gates);
  k_qkv<<<1536, 256, 0, stream>>>(hn, Wqkv, rope, q, k, v, rq, rk);
  k_gmlp1<<<1024, 256, 0, stream>>>(k, v, kpos, vpos, kw1, vw1, hh, hh2);
  k_g2<<<992, 256, 0, stream>>>(hh, hh2, kw2, vw2, ck, cv);
  k_cattn<<<256, 256, 0, stream>>>(q, ck, cv, mem_ck, mem_cv, gates, obuf, sel);
  k_fsw<<<dim3(16, 8, 16), 256, 0, stream>>>(rq, rk, v, sel, gates, obuf);
  k_out<<<512, 256, 0, stream>>>(obuf, Wo, out);
}

// Round 21
// 508.891 us; speedup vs baseline: 1.1354x; 1.0032x over previous
//
#include <hip/hip_runtime.h>
#include <hip/hip_bf16.h>
#include <math.h>

#define SCALE_ 0.17677669529663687f
typedef float v2f __attribute__((ext_vector_type(2)));

// two independent IEEE FMAs per instr; op_sel broadcasts a.lo / a.hi to both
// halves. Per-element order and rounding identical to scalar => bit-exact.
__device__ __forceinline__ void pk_lo(v2f& acc, v2f a, v2f b) {
  asm("v_pk_fma_f32 %0, %1, %2, %0 op_sel:[0,0,0] op_sel_hi:[0,1,1]"
      : "+v"(acc) : "v"(a), "v"(b));
}
__device__ __forceinline__ void pk_hi(v2f& acc, v2f a, v2f b) {
  asm("v_pk_fma_f32 %0, %1, %2, %0 op_sel:[1,0,0] op_sel_hi:[1,1,1]"
      : "+v"(acc) : "v"(a), "v"(b));
}

// fused: rope table (blocks 0-31) + per-ball pos mean (blocks 32-47)
__global__ __launch_bounds__(256) void k_pre(const float* __restrict__ pos,
                                             float* __restrict__ rope,
                                             float* __restrict__ pm) {
  __shared__ float ps[1536];
  if (blockIdx.x < 32) {
    int i = blockIdx.x * 256 + threadIdx.x;  // 8192
    int t = i >> 4, j = i & 15;
    float inv = powf(10000.f, -(float)j / 16.f);
    float ang = (float)t * inv;
    rope[2 * i]     = cosf(ang);
    rope[2 * i + 1] = sinf(ang);
  } else {
    int ball = blockIdx.x - 32;
    for (int i = threadIdx.x; i < 1536; i += 256) ps[i] = pos[(size_t)ball * 1536 + i];
    __syncthreads();
    if (threadIdx.x < 3) {
      int c = threadIdx.x;
      float s = 0.f;
      for (int t = 0; t < 512; ++t) s += ps[t * 3 + c];  // EXACT t-ascending (sel-sensitive)
      pm[ball * 3 + c] = s * (1.f / 512.f);
    }
  }
}

// hn + fused gates. EXACT sequential ss sum per token (sel-sensitive).
__global__ __launch_bounds__(256) void k_hn(const float* __restrict__ x,
                                            const float* __restrict__ pos,
                                            const float* __restrict__ pm,
                                            const float* __restrict__ Wpe,
                                            const float* __restrict__ bpe,
                                            const float* __restrict__ rmsw,
                                            const float* __restrict__ Wg,
                                            float* __restrict__ hn,
                                            float* __restrict__ gates) {
  __shared__ float hx[32][257];
  __shared__ float rr[32][3];
  __shared__ float invs[32];
  int tb = blockIdx.x * 32;  // 256 blocks
  if (threadIdx.x < 96) {
    int tok = threadIdx.x / 3, c = threadIdx.x % 3;
    rr[tok][c] = pos[(size_t)(tb + tok) * 3 + c] - pm[((tb + tok) >> 9) * 3 + c];
  }
  __syncthreads();
  for (int i = threadIdx.x; i < 8192; i += 256) {
    int tok = i >> 8, d = i & 255;
    float h = x[(size_t)(tb + tok) * 256 + d] + rr[tok][0] * Wpe[d] + rr[tok][1] * Wpe[256 + d]
            + rr[tok][2] * Wpe[512 + d] + bpe[d];
    hx[tok][d] = h;
  }
  __syncthreads();
  if (threadIdx.x < 32) {
    int tok = threadIdx.x;
    float ss = 0.f;
    for (int d = 0; d < 256; ++d) { float h = hx[tok][d]; ss += h * h; }
    invs[tok] = 1.f / sqrtf(ss * (1.f / 256.f) + 1e-6f);
  }
  __syncthreads();
  for (int i = threadIdx.x; i < 8192; i += 256) {
    int tok = i >> 8, d = i & 255;
    float hv = hx[tok][d] * invs[tok] * rmsw[d];
    hn[(size_t)(tb + tok) * 256 + d] = hv;
    hx[tok][d] = hv;
  }
  __syncthreads();
  for (int g = threadIdx.x; g < 768; g += 256) {
    int tok = g / 24, j = g % 24;
    float s = 0.f;
    for (int d = 0; d < 256; ++d) s += hx[tok][d] * Wg[d * 24 + j];
    gates[(size_t)(tb + tok) * 24 + j] = 1.f / (1.f + expf(-s));
  }
}

// qkv = hn @ Wqkv, 64x64, transposed As[32][68], pk_fma, b128 reads, fused RoPE.
__global__ __launch_bounds__(256) void k_qkv(const float* __restrict__ A,
                                             const float* __restrict__ B,
                                             const float* __restrict__ rope,
                                             float* __restrict__ qo,
                                             float* __restrict__ ko,
                                             float* __restrict__ vo,
                                             float* __restrict__ rqo,
                                             float* __restrict__ rko) {
  __shared__ __align__(16) float As[32][68];
  __shared__ __align__(16) float Bs[32][68];
  const int bid = blockIdx.x;            // 1536 = 8 xcd * 16 m * 12 n
  const int xcd = bid & 7;
  const int idx = bid >> 3;
  const int m0 = (xcd * 16 + (idx & 15)) * 64;
  const int n0 = (idx >> 4) * 64;
  const int tid = threadIdx.x;
  const int tx = tid & 15, ty = tid >> 4;
  v2f acc2[4][2] = {};
  for (int k0 = 0; k0 < 256; k0 += 32) {
#pragma unroll
    for (int i = 0; i < 2; ++i) {
      int li = tid + i * 256;
      int mm = li >> 3, c4 = li & 7;
      float4 a4 = *reinterpret_cast<const float4*>(&A[(size_t)(m0 + mm) * 256 + k0 + c4 * 4]);
      As[c4 * 4 + 0][mm] = a4.x; As[c4 * 4 + 1][mm] = a4.y;
      As[c4 * 4 + 2][mm] = a4.z; As[c4 * 4 + 3][mm] = a4.w;
    }
#pragma unroll
    for (int i = 0; i < 2; ++i) {
      int li = tid + i * 256;
      int r = li >> 4, c4 = li & 15;
      float4 b4 = *reinterpret_cast<const float4*>(&B[(size_t)(k0 + r) * 768 + n0 + c4 * 4]);
      *reinterpret_cast<float4*>(&Bs[r][c4 * 4]) = b4;
    }
    __syncthreads();
#pragma unroll
    for (int kk = 0; kk < 32; ++kk) {
      float4 a4 = *reinterpret_cast<const float4*>(&As[kk][ty * 4]);
      float4 b4 = *reinterpret_cast<const float4*>(&Bs[kk][tx * 4]);
      v2f a01 = {a4.x, a4.y}, a23 = {a4.z, a4.w};
      v2f blo = {b4.x, b4.y}, bhi = {b4.z, b4.w};
      pk_lo(acc2[0][0], a01, blo); pk_lo(acc2[0][1], a01, bhi);
      pk_hi(acc2[1][0], a01, blo); pk_hi(acc2[1][1], a01, bhi);
      pk_lo(acc2[2][0], a23, blo); pk_lo(acc2[2][1], a23, bhi);
      pk_hi(acc2[3][0], a23, blo); pk_hi(acc2[3][1], a23, bhi);
    }
    __syncthreads();
  }
#pragma unroll
  for (int i = 0; i < 4; ++i) {
    int row = m0 + ty * 4 + i;
    int nb = row >> 9, t = row & 511;
#pragma unroll
    for (int j = 0; j < 4; j += 2) {
      int col = n0 + tx * 4 + j;
      int which = col >> 8, cj = col & 255;
      int h = cj >> 5, d = cj & 31;
      float v1 = (j == 0) ? acc2[i][0].x : acc2[i][1].x;
      float v2 = (j == 0) ? acc2[i][0].y : acc2[i][1].y;
      size_t base = ((size_t)(nb * 8 + h) * 512 + t) * 32 + d;
      if (which == 0) {
        qo[base] = v1; qo[base + 1] = v2;
        int p = d >> 1;
        float cc = rope[(t * 16 + p) * 2], ss = rope[(t * 16 + p) * 2 + 1];
        rqo[base] = v1 * cc - v2 * ss; rqo[base + 1] = v1 * ss + v2 * cc;
      } else if (which == 1) {
        ko[base] = v1; ko[base + 1] = v2;
        int p = d >> 1;
        float cc = rope[(t * 16 + p) * 2], ss = rope[(t * 16 + p) * 2 + 1];
        rko[base] = v1 * cc - v2 * ss; rko[base + 1] = v1 * ss + v2 * cc;
      } else {
        vo[base] = v1; vo[base + 1] = v2;
      }
    }
  }
}

// gMLP layer 1, BOTH halves, 1024 blocks: 64x128 block tile, 4x8 per thread.
// Per kk: 1 b128 A-read + 2 b128 B-reads feed 32 products (16 pk) =>
// 114 FLOP/LDS-cycle vs 85 for the 64x64 tile. K ascending => bit-exact.
__global__ __launch_bounds__(256) void k_gmlp1(const float* __restrict__ ksrc,
                                               const float* __restrict__ vsrc,
                                               const float* __restrict__ kpos,
                                               const float* __restrict__ vpos,
                                               const float* __restrict__ kw1,
                                               const float* __restrict__ vw1,
                                               float* __restrict__ hb0,
                                               float* __restrict__ hb1) {
  __shared__ __align__(16) float As[32][68];
  __shared__ __align__(16) float Bs[32][132];
  const int half = blockIdx.x >> 9;      // 0:k, 1:v
  const int bid  = blockIdx.x & 511;
  const float* kv   = half ? vsrc : ksrc;
  const float* posw = half ? vpos : kpos;
  const float* w1   = half ? vw1  : kw1;
  float* hb         = half ? hb1  : hb0;
  const int xcd = bid & 7;
  const int idx = bid >> 3;            // 0..63
  const int mt  = idx & 7;             // 8 m-tiles of 64
  const int pn  = xcd * 8 + (idx >> 3);  // 0..63 panel (np,h)
  const int np  = pn & 7;
  const int h   = pn >> 3;
  const int n0 = np * 128;
  const int m0 = mt * 64;
  const int tid = threadIdx.x;
  const int tx = tid & 15, ty = tid >> 4;  // tx: 8-col group, ty: 4-row group
  const float* pw = posw + h * 1024;
  v2f acc2[4][4] = {};
  for (int k0 = 0; k0 < 1024; k0 += 32) {
#pragma unroll
    for (int i = 0; i < 2; ++i) {
      int li = tid + i * 256;
      int mm = li >> 3, c4 = li & 7;
      int row = m0 + mm;
      float4 av = {0.f, 0.f, 0.f, 0.f};
      if (row < 496) {
        int nb = row / 31, bb = row % 31;
        float4 k4 = *reinterpret_cast<const float4*>(
            &kv[((size_t)(nb * 8 + h) * 512 + bb * 16) * 32 + k0 + c4 * 4]);
        float4 p4 = *reinterpret_cast<const float4*>(&pw[k0 + c4 * 4]);
        av.x = k4.x + p4.x; av.y = k4.y + p4.y; av.z = k4.z + p4.z; av.w = k4.w + p4.w;
      }
      As[c4 * 4 + 0][mm] = av.x; As[c4 * 4 + 1][mm] = av.y;
      As[c4 * 4 + 2][mm] = av.z; As[c4 * 4 + 3][mm] = av.w;
    }
#pragma unroll
    for (int i = 0; i < 4; ++i) {
      int li = tid + i * 256;
      int r = li >> 5, c4 = li & 31;
      float4 b4 = *reinterpret_cast<const float4*>(
          &w1[(size_t)h * 1048576 + (size_t)(k0 + r) * 1024 + n0 + c4 * 4]);
      *reinterpret_cast<float4*>(&Bs[r][c4 * 4]) = b4;
    }
    __syncthreads();
#pragma unroll
    for (int kk = 0; kk < 32; ++kk) {
      float4 a4  = *reinterpret_cast<const float4*>(&As[kk][ty * 4]);
      float4 bl4 = *reinterpret_cast<const float4*>(&Bs[kk][tx * 8]);
      float4 bh4 = *reinterpret_cast<const float4*>(&Bs[kk][tx * 8 + 4]);
      v2f a01 = {a4.x, a4.y}, a23 = {a4.z, a4.w};
      v2f b0 = {bl4.x, bl4.y}, b1 = {bl4.z, bl4.w};
      v2f b2 = {bh4.x, bh4.y}, b3 = {bh4.z, bh4.w};
      pk_lo(acc2[0][0], a01, b0); pk_lo(acc2[0][1], a01, b1);
      pk_lo(acc2[0][2], a01, b2); pk_lo(acc2[0][3], a01, b3);
      pk_hi(acc2[1][0], a01, b0); pk_hi(acc2[1][1], a01, b1);
      pk_hi(acc2[1][2], a01, b2); pk_hi(acc2[1][3], a01, b3);
      pk_lo(acc2[2][0], a23, b0); pk_lo(acc2[2][1], a23, b1);
      pk_lo(acc2[2][2], a23, b2); pk_lo(acc2[2][3], a23, b3);
      pk_hi(acc2[3][0], a23, b0); pk_hi(acc2[3][1], a23, b1);
      pk_hi(acc2[3][2], a23, b2); pk_hi(acc2[3][3], a23, b3);
    }
    __syncthreads();
  }
#pragma unroll
  for (int i = 0; i < 4; ++i) {
    int row = m0 + ty * 4 + i;
    if (row < 496) {
      float* dst = &hb[((size_t)h * 496 + row) * 1024 + n0 + tx * 8];
#pragma unroll
      for (int jj = 0; jj < 4; ++jj) {
        dst[2 * jj]     = fmaxf(acc2[i][jj].x, 0.f);
        dst[2 * jj + 1] = fmaxf(acc2[i][jj].y, 0.f);
      }
    }
  }
}

// gMLP out for BOTH halves in one launch; per-output EXACT ascending-i sum.
__global__ __launch_bounds__(256) void k_g2(const float* __restrict__ hh0,
                                            const float* __restrict__ hh1,
                                            const float* __restrict__ kw2,
                                            const float* __restrict__ vw2,
                                            float* __restrict__ ck,
                                            float* __restrict__ cv) {
  int gid = blockIdx.x * 256 + threadIdx.x;  // 253952 = 2*126976
  int half = gid >= 126976;
  int lid = gid - half * 126976;
  const float* hh = half ? hh1 : hh0;
  const float* w2 = half ? vw2 : kw2;
  float* outp = half ? cv : ck;
  int o = lid & 31;
  int rem = lid >> 5;
  int h = rem / 496, row = rem % 496;
  int nb = row / 31, bb = row % 31;
  const float* hr = hh + (size_t)rem * 1024;
  const float* w2p = w2 + (size_t)h * 32768 + o;
  float s = 0.f;
  for (int i = 0; i < 1024; i += 4) {
    float4 h4 = *reinterpret_cast<const float4*>(&hr[i]);
    s += h4.x * w2p[(size_t)i * 32];
    s += h4.y * w2p[(size_t)(i + 1) * 32];
    s += h4.z * w2p[(size_t)(i + 2) * 32];
    s += h4.w * w2p[(size_t)(i + 3) * 32];
  }
  outp[((size_t)(nb * 8 + h) * 31 + bb) * 32 + o] = s;
}

// compressed attention: 2 blocks per nh (256 total); per-t math identical.
__global__ __launch_bounds__(256) void k_cattn(const float* __restrict__ q,
                                               const float* __restrict__ ck,
                                               const float* __restrict__ cv,
                                               const float* __restrict__ mem_ck,
                                               const float* __restrict__ mem_cv,
                                               const float* __restrict__ gates,
                                               float* __restrict__ obuf,
                                               int* __restrict__ sel) {
  int nh = blockIdx.x >> 1;
  int h = nh & 7, ball = nh >> 3;
  int t = (blockIdx.x & 1) * 256 + threadIdx.x;
  __shared__ float kf[32][33], vf[32][33];
  for (int i = threadIdx.x; i < 1024; i += 256) {
    int j = i >> 5, d = i & 31;
    kf[j][d] = (j == 0) ? mem_ck[h * 32 + d] : ck[((size_t)nh * 31 + j - 1) * 32 + d];
    vf[j][d] = (j == 0) ? mem_cv[h * 32 + d] : cv[((size_t)nh * 31 + j - 1) * 32 + d];
  }
  __syncthreads();
  const float* qp = q + ((size_t)nh * 512 + t) * 32;
  float qr[32];
#pragma unroll
  for (int d = 0; d < 32; ++d) qr[d] = qp[d];
  float sc[32];
  float mx = -INFINITY;
#pragma unroll
  for (int j = 0; j < 32; ++j) {
    float s = -INFINITY;
    bool valid = (j == 0) || (t >= (j - 1) * 16 + 31);
    if (valid) {
      s = 0.f;
      for (int d = 0; d < 32; ++d) s += qr[d] * kf[j][d];
      s *= SCALE_;
    }
    sc[j] = s;
    mx = fmaxf(mx, s);
  }
  float e[32];
  float den = 0.f;
#pragma unroll
  for (int j = 0; j < 32; ++j) { e[j] = expf(sc[j] - mx); den += e[j]; }
  float num[32];
#pragma unroll
  for (int d = 0; d < 32; ++d) num[d] = 0.f;
#pragma unroll
  for (int j = 0; j < 32; ++j) {
    float p = e[j];
    for (int d = 0; d < 32; ++d) num[d] += p * vf[j][d];
  }
  float inv = 1.f / den;
  float g0 = gates[(size_t)(ball * 512 + t) * 24 + h * 3];
  float* op = obuf + (size_t)(ball * 512 + t) * 256 + h * 32;
  for (int d = 0; d < 32; ++d) op[d] = num[d] * inv * g0;

  int s_idx = 0;
  if (t >= 32) {
    int fn = t >> 5;
    float best = -INFINITY;
    for (int f = 0; f < fn; ++f) {
      float im = 0.f;
#pragma unroll
      for (int j = 0; j < 31; ++j) {
        int a = j * 16, b2 = a + 32, fa = f * 32, fb = fa + 32;
        int lo = a > fa ? a : fa;
        int hi = b2 < fb ? b2 : fb;
        if (hi > lo) im += e[j + 1] * (float)(hi - lo) * (1.f / 32.f);
      }
      if (im > best) { best = im; s_idx = f; }
    }
  }
  sel[(size_t)nh * 512 + t] = s_idx;
}

// merged fine + sliding-window attention. obuf order: (c + f*g1) + sw*g2.
__global__ __launch_bounds__(256) void k_fsw(const float* __restrict__ rq,
                                             const float* __restrict__ rk,
                                             const float* __restrict__ v,
                                             const int* __restrict__ sel,
                                             const float* __restrict__ gates,
                                             float* __restrict__ obuf) {
  int b = blockIdx.x, h = blockIdx.y, nb = blockIdx.z;
  int nh = nb * 8 + h;
  __shared__ float rqs[32][33], k2s[64][33], v2s[64][33];
  for (int i = threadIdx.x; i < 1024; i += 256) {
    int r = i >> 5, d = i & 31;
    rqs[r][d] = rq[((size_t)nh * 512 + b * 32 + r) * 32 + d];
  }
  for (int i = threadIdx.x; i < 2048; i += 256) {
    int r = i >> 5, d = i & 31;
    int tk = (b - 1) * 32 + r;
    float kk_ = 0.f, vv_ = 0.f;
    if (tk >= 0) {
      kk_ = rk[((size_t)nh * 512 + tk) * 32 + d];
      vv_ = v[((size_t)nh * 512 + tk) * 32 + d];
    }
    k2s[r][d] = kk_;
    v2s[r][d] = vv_;
  }
  __syncthreads();
  int qi = threadIdx.x >> 3, l = threadIdx.x & 7;
  int t = b * 32 + qi;

  // ---------- fine attention ----------
  int sb = sel[(size_t)nh * 512 + t];
  bool hs = (t >= 32);
  float fo[4];
  {
    float p[8];
    float mx = -INFINITY;
#pragma unroll
    for (int kk2 = 0; kk2 < 8; ++kk2) {
      int kk = l * 8 + kk2;
      float s = -INFINITY;
      if (kk < 32) {
        if (qi >= kk) {
          s = 0.f;
#pragma unroll
          for (int d = 0; d < 32; ++d) s += rqs[qi][d] * k2s[32 + kk][d];
          s *= SCALE_;
        }
      } else if (hs) {
        const float* kp = rk + ((size_t)nh * 512 + sb * 32 + (kk - 32)) * 32;
        s = 0.f;
#pragma unroll
        for (int d = 0; d < 32; ++d) s += rqs[qi][d] * kp[d];
        s *= SCALE_;
      }
      p[kk2] = s;
      mx = fmaxf(mx, s);
    }
#pragma unroll
    for (int off = 4; off; off >>= 1) mx = fmaxf(mx, __shfl_xor(mx, off, 8));
    float sum = 0.f;
#pragma unroll
    for (int kk2 = 0; kk2 < 8; ++kk2) { p[kk2] = expf(p[kk2] - mx); sum += p[kk2]; }
#pragma unroll
    for (int off = 4; off; off >>= 1) sum += __shfl_xor(sum, off, 8);
    float inv = 1.f / sum;
    float acc[32];
#pragma unroll
    for (int d = 0; d < 32; ++d) acc[d] = 0.f;
#pragma unroll
    for (int kk2 = 0; kk2 < 8; ++kk2) {
      int kk = l * 8 + kk2;
      float pwt = p[kk2] * inv;
      if (kk < 32) {
#pragma unroll
        for (int d = 0; d < 32; ++d) acc[d] += pwt * v2s[32 + kk][d];
      } else if (hs) {
        const float* vp = v + ((size_t)nh * 512 + sb * 32 + (kk - 32)) * 32;
#pragma unroll
        for (int d = 0; d < 32; ++d) acc[d] += pwt * vp[d];
      }
    }
#pragma unroll
    for (int off = 4; off; off >>= 1) {
#pragma unroll
      for (int d = 0; d < 32; ++d) acc[d] += __shfl_xor(acc[d], off, 8);
    }
#pragma unroll
    for (int j = 0; j < 4; ++j) fo[j] = acc[l * 4 + j];
  }

  // ---------- sliding window ----------
  float so[4];
  {
    float p[8];
    float mx = -INFINITY;
#pragma unroll
    for (int kk2 = 0; kk2 < 8; ++kk2) {
      int kk = l * 8 + kk2;
      bool valid = (kk > qi) && (kk <= qi + 32) && ((b > 0) || (kk >= 32));
      float s = -INFINITY;
      if (valid) {
        s = 0.f;
#pragma unroll
        for (int d = 0; d < 32; ++d) s += rqs[qi][d] * k2s[kk][d];
        s *= SCALE_;
      }
      p[kk2] = s;
      mx = fmaxf(mx, s);
    }
#pragma unroll
    for (int off = 4; off; off >>= 1) mx = fmaxf(mx, __shfl_xor(mx, off, 8));
    float sum = 0.f;
#pragma unroll
    for (int kk2 = 0; kk2 < 8; ++kk2) { p[kk2] = expf(p[kk2] - mx); sum += p[kk2]; }
#pragma unroll
    for (int off = 4; off; off >>= 1) sum += __shfl_xor(sum, off, 8);
    float inv = 1.f / sum;
    float acc[32];
#pragma unroll
    for (int d = 0; d < 32; ++d) acc[d] = 0.f;
#pragma unroll
    for (int kk2 = 0; kk2 < 8; ++kk2) {
      int kk = l * 8 + kk2;
      float pwt = p[kk2] * inv;
#pragma unroll
      for (int d = 0; d < 32; ++d) acc[d] += pwt * v2s[kk][d];
    }
#pragma unroll
    for (int off = 4; off; off >>= 1) {
#pragma unroll
      for (int d = 0; d < 32; ++d) acc[d] += __shfl_xor(acc[d], off, 8);
    }
#pragma unroll
    for (int j = 0; j < 4; ++j) so[j] = acc[l * 4 + j];
  }

  float g1 = gates[(size_t)(nb * 512 + t) * 24 + h * 3 + 1];
  float g2 = gates[(size_t)(nb * 512 + t) * 24 + h * 3 + 2];
  float* op = obuf + (size_t)(nb * 512 + t) * 256 + h * 32;
#pragma unroll
  for (int j = 0; j < 4; ++j) {
    float cur = op[l * 4 + j];
    cur += fo[j] * g1;
    cur += so[j] * g2;
    op[l * 4 + j] = cur;
  }
}

// final projection: 64x64, transposed As[32][68], pk_fma, XCD swizzle.
__global__ __launch_bounds__(256) void k_out(const float* __restrict__ A,
                                             const float* __restrict__ B,
                                             float* __restrict__ C) {
  __shared__ __align__(16) float As[32][68];
  __shared__ __align__(16) float Bs[32][68];
  const int bid = blockIdx.x;            // 512 = 8 xcd * 16 m * 4 n
  const int xcd = bid & 7;
  const int idx = bid >> 3;
  const int m0 = (xcd * 16 + (idx & 15)) * 64;
  const int n0 = (idx >> 4) * 64;
  const int tid = threadIdx.x;
  const int tx = tid & 15, ty = tid >> 4;
  v2f acc2[4][2] = {};
  for (int k0 = 0; k0 < 256; k0 += 32) {
#pragma unroll
    for (int i = 0; i < 2; ++i) {
      int li = tid + i * 256;
      int mm = li >> 3, c4 = li & 7;
      float4 a4 = *reinterpret_cast<const float4*>(&A[(size_t)(m0 + mm) * 256 + k0 + c4 * 4]);
      As[c4 * 4 + 0][mm] = a4.x; As[c4 * 4 + 1][mm] = a4.y;
      As[c4 * 4 + 2][mm] = a4.z; As[c4 * 4 + 3][mm] = a4.w;
    }
#pragma unroll
    for (int i = 0; i < 2; ++i) {
      int li = tid + i * 256;
      int r = li >> 4, c4 = li & 15;
      float4 b4 = *reinterpret_cast<const float4*>(&B[(size_t)(k0 + r) * 256 + n0 + c4 * 4]);
      *reinterpret_cast<float4*>(&Bs[r][c4 * 4]) = b4;
    }
    __syncthreads();
#pragma unroll
    for (int kk = 0; kk < 32; ++kk) {
      float4 a4 = *reinterpret_cast<const float4*>(&As[kk][ty * 4]);
      float4 b4 = *reinterpret_cast<const float4*>(&Bs[kk][tx * 4]);
      v2f a01 = {a4.x, a4.y}, a23 = {a4.z, a4.w};
      v2f blo = {b4.x, b4.y}, bhi = {b4.z, b4.w};
      pk_lo(acc2[0][0], a01, blo); pk_lo(acc2[0][1], a01, bhi);
      pk_hi(acc2[1][0], a01, blo); pk_hi(acc2[1][1], a01, bhi);
      pk_lo(acc2[2][0], a23, blo); pk_lo(acc2[2][1], a23, bhi);
      pk_hi(acc2[3][0], a23, blo); pk_hi(acc2[3][1], a23, bhi);
    }
    __syncthreads();
  }
#pragma unroll
  for (int i = 0; i < 4; ++i) {
    int row = m0 + ty * 4 + i;
    float* dst = &C[(size_t)row * 256 + n0 + tx * 4];
    dst[0] = acc2[i][0].x;
    dst[1] = acc2[i][0].y;
    dst[2] = acc2[i][1].x;
    dst[3] = acc2[i][1].y;
  }
}

extern "C" void kernel_launch(void* const* d_in, const int* in_sizes, int n_in,
                              void* d_out, int out_size, void* d_ws, size_t ws_size,
                              hipStream_t stream) {
  const float* x      = (const float*)d_in[0];
  const float* pos    = (const float*)d_in[1];
  const float* Wpe    = (const float*)d_in[2];
  const float* bpe    = (const float*)d_in[3];
  const float* rms_w  = (const float*)d_in[4];
  const float* Wqkv   = (const float*)d_in[5];
  const float* kpos   = (const float*)d_in[6];
  const float* vpos   = (const float*)d_in[7];
  const float* kw1    = (const float*)d_in[8];
  const float* kw2    = (const float*)d_in[9];
  const float* vw1    = (const float*)d_in[10];
  const float* vw2    = (const float*)d_in[11];
  const float* mem_ck = (const float*)d_in[12];
  const float* mem_cv = (const float*)d_in[13];
  const float* Wg     = (const float*)d_in[14];
  const float* Wo     = (const float*)d_in[15];
  float* out = (float*)d_out;

  float* ws = (float*)d_ws;
  const size_t TOK = 2097152;  // 8192*256
  float* q     = ws;
  float* k     = ws + TOK;
  float* v     = ws + 2 * TOK;
  float* rq    = ws + 3 * TOK;
  float* rk    = ws + 4 * TOK;
  float* hn    = ws + 5 * TOK;
  float* obuf  = ws + 6 * TOK;
  float* hh    = ws + 7 * TOK;       // 4,063,232
  float* hh2   = hn;                 // aliases hn+obuf span (hn dead after k_qkv)
  float* ck    = hh + 4063232;
  float* cv    = ck + 126976;
  float* gates = cv + 126976;
  float* rope  = gates + 196608;
  float* pm    = rope + 16384;
  int*   sel   = (int*)(pm + 64);

  k_pre<<<48, 256, 0, stream>>>(pos, rope, pm);
  k_hn<<<256, 256, 0, stream>>>(x, pos, pm, Wpe, bpe, rms_w, Wg, hn, gates);
  k_qkv<<<1536, 256, 0, stream>>>(hn, Wqkv, rope, q, k, v, rq, rk);
  k_gmlp1<<<1024, 256, 0, stream>>>(k, v, kpos, vpos, kw1, vw1, hh, hh2);
  k_g2<<<992, 256, 0, stream>>>(hh, hh2, kw2, vw2, ck, cv);
  k_cattn<<<256, 256, 0, stream>>>(q, ck, cv, mem_ck, mem_cv, gates, obuf, sel);
  k_fsw<<<dim3(16, 8, 16), 256, 0, stream>>>(rq, rk, v, sel, gates, obuf);
  k_out<<<512, 256, 0, stream>>>(obuf, Wo, out);
}